// Round 14
// baseline (110.388 us; speedup 1.0000x reference)
//
#include <hip/hip_runtime.h>
#include <stdint.h>

#define NPIX 9216   // 96*96
#define CIN 64
#define DD 24
#define DP 32       // padded head dim (24 -> 32; K cols 24-31 zero, V rows: 24=ones, 25-31=zero)
#define JW 576      // j per wave (j-half 4608 / 8 waves)
#define NIT 9       // 576 / 64

typedef __attribute__((ext_vector_type(8))) short short8;   // 8 bf16
typedef __attribute__((ext_vector_type(4))) float f32x4;
typedef __attribute__((ext_vector_type(4))) unsigned int u32x4;

__device__ __forceinline__ unsigned short f2bf(float f) {
    unsigned int u = __builtin_bit_cast(unsigned int, f);
    u += 0x7fffu + ((u >> 16) & 1u);
    return (unsigned short)(u >> 16);
}
// packed f32x2 -> bf16x2 in one VALU op (T12 recipe; dst.lo = first operand)
__device__ __forceinline__ unsigned int pkbf(float lo, float hi) {
    unsigned int r;
    asm("v_cvt_pk_bf16_f32 %0, %1, %2" : "=v"(r) : "v"(lo), "v"(hi));
    return r;
}

// ---------------- Kernel 1: QKV projection (one proj per thread, r13 verbatim) -------
__global__ __launch_bounds__(256) void qkv_proj_kernel(
    const float* __restrict__ x,
    const float* __restrict__ wq, const float* __restrict__ bq,
    const float* __restrict__ wk, const float* __restrict__ bk,
    const float* __restrict__ wv, const float* __restrict__ bv,
    unsigned short* __restrict__ qr, unsigned short* __restrict__ kr,
    unsigned short* __restrict__ vdn)
{
    const int p = blockIdx.y;
    const int tid = blockIdx.x * 256 + threadIdx.x;
    const int b = tid / NPIX;
    const int n = tid - b * NPIX;
    const float* xb = x + (size_t)b * CIN * NPIX + n;
    float xv[CIN];
#pragma unroll
    for (int c = 0; c < CIN; ++c) xv[c] = xb[(size_t)c * NPIX];

    const float* wm = (p == 0) ? wq : (p == 1) ? wk : wv;
    const float* bm = (p == 0) ? bq : (p == 1) ? bk : bv;

    float acc[DD];
#pragma unroll
    for (int d = 0; d < DD; ++d) acc[d] = bm[d];
#pragma unroll 4
    for (int c = 0; c < CIN; ++c) {
        const float xc = xv[c];
#pragma unroll
        for (int d = 0; d < DD; ++d) acc[d] = fmaf(wm[d * CIN + c], xc, acc[d]);
    }

    if (p == 2) {           // V: d-major rows 0..23 data, 24 = 1.0, 25..31 = 0
        const size_t vbase = (size_t)b * DP * NPIX + n;
#pragma unroll
        for (int d = 0; d < DD; ++d) vdn[vbase + (size_t)d * NPIX] = f2bf(acc[d]);
        vdn[vbase + (size_t)24 * NPIX] = (unsigned short)0x3F80;
#pragma unroll
        for (int d = 25; d < DP; ++d) vdn[vbase + (size_t)d * NPIX] = 0;
    } else {
        alignas(16) unsigned short row[DP];
        const float sc = (p == 0) ? (float)(0.20412414523193154 * 1.4426950408889634) : 1.0f;
#pragma unroll
        for (int d = 0; d < DD; ++d) row[d] = f2bf(acc[d] * sc);
#pragma unroll
        for (int d = DD; d < DP; ++d) row[d] = 0;
        unsigned short* dst = ((p == 0) ? qr : kr) + (size_t)(b * NPIX + n) * DP;
        const u32x4* r4 = (const u32x4*)row;
#pragma unroll
        for (int i = 0; i < 4; ++i) ((u32x4*)dst)[i] = r4[i];
    }
}

// ---------------- Kernel 2: flash attention (64q/wave, barrier-free, 8 waves/block) --
// grid (144 tiles, 2 j-halves, 4 batches); 512 threads = 8 waves, wave w owns 576 j of
// the block's half. Main loop = r13-verified, byte-identical (direct-global fragments,
// perm-absorbed K addressing, no LDS, no barriers). 2x r13's wave demand (36/CU) at
// the same 36.9 KB LDS (epilogue only) -> 4 blocks/CU, double residency for latency
// hiding. Epilogue: waves 0-3 write om, barrier, waves 4-7 accumulate (disjoint
// addresses), barrier, merge. Softmax without max subtraction (r9-verified).
__global__ __launch_bounds__(512) void attn_kernel(
    const unsigned short* __restrict__ qr,
    const unsigned short* __restrict__ kr,
    const unsigned short* __restrict__ vdn,
    float* __restrict__ part)
{
    __shared__ float om[4 * 64 * 36];   // epilogue merge only; col 24 = denom

    const int tile = blockIdx.x, jh = blockIdx.y, b = blockIdx.z;
    const int t = threadIdx.x;
    const int w = t >> 6, lane = t & 63;
    const int g = lane >> 4, c = lane & 15;

    const int qbase = tile * 64 + c;
    const unsigned short* qp = qr + (size_t)b * NPIX * DP;
    const short8 qfA = *(const short8*)(qp + (size_t)(qbase +  0) * DP + g * 8);
    const short8 qfB = *(const short8*)(qp + (size_t)(qbase + 16) * DP + g * 8);
    const short8 qfC = *(const short8*)(qp + (size_t)(qbase + 32) * DP + g * 8);
    const short8 qfD = *(const short8*)(qp + (size_t)(qbase + 48) * DP + g * 8);

    const unsigned short* kb = kr + (size_t)b * NPIX * DP;
    const unsigned short* vb = vdn + (size_t)b * DP * NPIX;
    const int jbase = jh * 4608 + w * JW;

    // K fragment base (r13-verified): lane (g,c) -> K row perm_inv(c), dp chunk g*8;
    // frag element offsets {0, 128, 1024, 1152} (= rows {0,4,32,36}).
    const int jinv0 = ((c >> 3) & 1) * 16 + ((c >> 2) & 1) * 8 + (c & 3);
    const unsigned short* kp = kb + ((size_t)(jbase + jinv0)) * DP + g * 8;
    // V fragment bases: rows d = c and d = 16+c, j chunk g*8 (+32 for the second half).
    const unsigned short* vpl = vb + (size_t)c * NPIX + jbase + g * 8;
    const unsigned short* vph = vpl + (size_t)16 * NPIX;

    f32x4 aA0 = {0.f,0.f,0.f,0.f}, aA1 = aA0;   // per q-frag: O^T[d][q=c]; row 24 = denom
    f32x4 aB0 = aA0, aB1 = aA0;
    f32x4 aC0 = aA0, aC1 = aA0;
    f32x4 aD0 = aA0, aD1 = aA0;
    const f32x4 zf = {0.f, 0.f, 0.f, 0.f};

    // prefetch K frags for tile 0
    short8 nk0 = *(const short8*)(kp);
    short8 nk1 = *(const short8*)(kp + 128);
    short8 nk2 = *(const short8*)(kp + 1024);
    short8 nk3 = *(const short8*)(kp + 1152);

    for (int it = 0; it < NIT; ++it) {
        const short8 kf0 = nk0, kf1 = nk1, kf2 = nk2, kf3 = nk3;
        // V loads for this iter: consumed after S-MFMA + softmax -> self-hiding
        const short8 vl0 = *(const short8*)(vpl);
        const short8 vh0 = *(const short8*)(vph);
        const short8 vl1 = *(const short8*)(vpl + 32);
        const short8 vh1 = *(const short8*)(vph + 32);
        vpl += 64; vph += 64;
        if (it + 1 < NIT) {     // prefetch next K tile (64 rows * 64B = +2048 elems)
            kp += 2048;
            nk0 = *(const short8*)(kp);
            nk1 = *(const short8*)(kp + 128);
            nk2 = *(const short8*)(kp + 1024);
            nk3 = *(const short8*)(kp + 1152);
        }

        // ======== q-frag pair A,B: r12/r13-verified body, verbatim ========
        {
            __builtin_amdgcn_s_setprio(1);
            f32x4 sA0 = __builtin_amdgcn_mfma_f32_16x16x32_bf16(kf0, qfA, zf, 0, 0, 0);
            f32x4 sA1 = __builtin_amdgcn_mfma_f32_16x16x32_bf16(kf1, qfA, zf, 0, 0, 0);
            f32x4 sA2 = __builtin_amdgcn_mfma_f32_16x16x32_bf16(kf2, qfA, zf, 0, 0, 0);
            f32x4 sA3 = __builtin_amdgcn_mfma_f32_16x16x32_bf16(kf3, qfA, zf, 0, 0, 0);
            f32x4 sB0 = __builtin_amdgcn_mfma_f32_16x16x32_bf16(kf0, qfB, zf, 0, 0, 0);
            f32x4 sB1 = __builtin_amdgcn_mfma_f32_16x16x32_bf16(kf1, qfB, zf, 0, 0, 0);
            f32x4 sB2 = __builtin_amdgcn_mfma_f32_16x16x32_bf16(kf2, qfB, zf, 0, 0, 0);
            f32x4 sB3 = __builtin_amdgcn_mfma_f32_16x16x32_bf16(kf3, qfB, zf, 0, 0, 0);
            __builtin_amdgcn_s_setprio(0);

            union { short8 s8; unsigned int u32[4]; } fa0, fa1, fb0, fb1;
            {
                float p0[4], p1[4], p2[4], p3[4];
#pragma unroll
                for (int r = 0; r < 4; ++r) {
                    p0[r] = __builtin_amdgcn_exp2f(sA0[r]);
                    p1[r] = __builtin_amdgcn_exp2f(sA1[r]);
                    p2[r] = __builtin_amdgcn_exp2f(sA2[r]);
                    p3[r] = __builtin_amdgcn_exp2f(sA3[r]);
                }
                fa0.u32[0] = pkbf(p0[0], p0[1]); fa0.u32[1] = pkbf(p0[2], p0[3]);
                fa0.u32[2] = pkbf(p1[0], p1[1]); fa0.u32[3] = pkbf(p1[2], p1[3]);
                fa1.u32[0] = pkbf(p2[0], p2[1]); fa1.u32[1] = pkbf(p2[2], p2[3]);
                fa1.u32[2] = pkbf(p3[0], p3[1]); fa1.u32[3] = pkbf(p3[2], p3[3]);
            }
            {
                float p0[4], p1[4], p2[4], p3[4];
#pragma unroll
                for (int r = 0; r < 4; ++r) {
                    p0[r] = __builtin_amdgcn_exp2f(sB0[r]);
                    p1[r] = __builtin_amdgcn_exp2f(sB1[r]);
                    p2[r] = __builtin_amdgcn_exp2f(sB2[r]);
                    p3[r] = __builtin_amdgcn_exp2f(sB3[r]);
                }
                fb0.u32[0] = pkbf(p0[0], p0[1]); fb0.u32[1] = pkbf(p0[2], p0[3]);
                fb0.u32[2] = pkbf(p1[0], p1[1]); fb0.u32[3] = pkbf(p1[2], p1[3]);
                fb1.u32[0] = pkbf(p2[0], p2[1]); fb1.u32[1] = pkbf(p2[2], p2[3]);
                fb1.u32[2] = pkbf(p3[0], p3[1]); fb1.u32[3] = pkbf(p3[2], p3[3]);
            }

            __builtin_amdgcn_s_setprio(1);
            aA0 = __builtin_amdgcn_mfma_f32_16x16x32_bf16(vl0, fa0.s8, aA0, 0, 0, 0);
            aA1 = __builtin_amdgcn_mfma_f32_16x16x32_bf16(vh0, fa0.s8, aA1, 0, 0, 0);
            aA0 = __builtin_amdgcn_mfma_f32_16x16x32_bf16(vl1, fa1.s8, aA0, 0, 0, 0);
            aA1 = __builtin_amdgcn_mfma_f32_16x16x32_bf16(vh1, fa1.s8, aA1, 0, 0, 0);
            aB0 = __builtin_amdgcn_mfma_f32_16x16x32_bf16(vl0, fb0.s8, aB0, 0, 0, 0);
            aB1 = __builtin_amdgcn_mfma_f32_16x16x32_bf16(vh0, fb0.s8, aB1, 0, 0, 0);
            aB0 = __builtin_amdgcn_mfma_f32_16x16x32_bf16(vl1, fb1.s8, aB0, 0, 0, 0);
            aB1 = __builtin_amdgcn_mfma_f32_16x16x32_bf16(vh1, fb1.s8, aB1, 0, 0, 0);
            __builtin_amdgcn_s_setprio(0);
        }
        // ======== q-frag pair C,D: same verified body, kf/vf reused ========
        {
            __builtin_amdgcn_s_setprio(1);
            f32x4 sC0 = __builtin_amdgcn_mfma_f32_16x16x32_bf16(kf0, qfC, zf, 0, 0, 0);
            f32x4 sC1 = __builtin_amdgcn_mfma_f32_16x16x32_bf16(kf1, qfC, zf, 0, 0, 0);
            f32x4 sC2 = __builtin_amdgcn_mfma_f32_16x16x32_bf16(kf2, qfC, zf, 0, 0, 0);
            f32x4 sC3 = __builtin_amdgcn_mfma_f32_16x16x32_bf16(kf3, qfC, zf, 0, 0, 0);
            f32x4 sD0 = __builtin_amdgcn_mfma_f32_16x16x32_bf16(kf0, qfD, zf, 0, 0, 0);
            f32x4 sD1 = __builtin_amdgcn_mfma_f32_16x16x32_bf16(kf1, qfD, zf, 0, 0, 0);
            f32x4 sD2 = __builtin_amdgcn_mfma_f32_16x16x32_bf16(kf2, qfD, zf, 0, 0, 0);
            f32x4 sD3 = __builtin_amdgcn_mfma_f32_16x16x32_bf16(kf3, qfD, zf, 0, 0, 0);
            __builtin_amdgcn_s_setprio(0);

            union { short8 s8; unsigned int u32[4]; } fc0, fc1, fd0, fd1;
            {
                float p0[4], p1[4], p2[4], p3[4];
#pragma unroll
                for (int r = 0; r < 4; ++r) {
                    p0[r] = __builtin_amdgcn_exp2f(sC0[r]);
                    p1[r] = __builtin_amdgcn_exp2f(sC1[r]);
                    p2[r] = __builtin_amdgcn_exp2f(sC2[r]);
                    p3[r] = __builtin_amdgcn_exp2f(sC3[r]);
                }
                fc0.u32[0] = pkbf(p0[0], p0[1]); fc0.u32[1] = pkbf(p0[2], p0[3]);
                fc0.u32[2] = pkbf(p1[0], p1[1]); fc0.u32[3] = pkbf(p1[2], p1[3]);
                fc1.u32[0] = pkbf(p2[0], p2[1]); fc1.u32[1] = pkbf(p2[2], p2[3]);
                fc1.u32[2] = pkbf(p3[0], p3[1]); fc1.u32[3] = pkbf(p3[2], p3[3]);
            }
            {
                float p0[4], p1[4], p2[4], p3[4];
#pragma unroll
                for (int r = 0; r < 4; ++r) {
                    p0[r] = __builtin_amdgcn_exp2f(sD0[r]);
                    p1[r] = __builtin_amdgcn_exp2f(sD1[r]);
                    p2[r] = __builtin_amdgcn_exp2f(sD2[r]);
                    p3[r] = __builtin_amdgcn_exp2f(sD3[r]);
                }
                fd0.u32[0] = pkbf(p0[0], p0[1]); fd0.u32[1] = pkbf(p0[2], p0[3]);
                fd0.u32[2] = pkbf(p1[0], p1[1]); fd0.u32[3] = pkbf(p1[2], p1[3]);
                fd1.u32[0] = pkbf(p2[0], p2[1]); fd1.u32[1] = pkbf(p2[2], p2[3]);
                fd1.u32[2] = pkbf(p3[0], p3[1]); fd1.u32[3] = pkbf(p3[2], p3[3]);
            }

            __builtin_amdgcn_s_setprio(1);
            aC0 = __builtin_amdgcn_mfma_f32_16x16x32_bf16(vl0, fc0.s8, aC0, 0, 0, 0);
            aC1 = __builtin_amdgcn_mfma_f32_16x16x32_bf16(vh0, fc0.s8, aC1, 0, 0, 0);
            aC0 = __builtin_amdgcn_mfma_f32_16x16x32_bf16(vl1, fc1.s8, aC0, 0, 0, 0);
            aC1 = __builtin_amdgcn_mfma_f32_16x16x32_bf16(vh1, fc1.s8, aC1, 0, 0, 0);
            aD0 = __builtin_amdgcn_mfma_f32_16x16x32_bf16(vl0, fd0.s8, aD0, 0, 0, 0);
            aD1 = __builtin_amdgcn_mfma_f32_16x16x32_bf16(vh0, fd0.s8, aD1, 0, 0, 0);
            aD0 = __builtin_amdgcn_mfma_f32_16x16x32_bf16(vl1, fd1.s8, aD0, 0, 0, 0);
            aD1 = __builtin_amdgcn_mfma_f32_16x16x32_bf16(vh1, fd1.s8, aD1, 0, 0, 0);
            __builtin_amdgcn_s_setprio(0);
        }
    }

    // epilogue: waves 0-3 write om, barrier, waves 4-7 accumulate (disjoint addrs)
    const int pw = w & 3;
    float* s0 = om + (pw * 64 + c)      * 36 + 4 * g;
    float* s1 = om + (pw * 64 + 16 + c) * 36 + 4 * g;
    float* s2 = om + (pw * 64 + 32 + c) * 36 + 4 * g;
    float* s3 = om + (pw * 64 + 48 + c) * 36 + 4 * g;
    if (w < 4) {
        *(f32x4*)(s0) = aA0; *(f32x4*)(s0 + 16) = aA1;
        *(f32x4*)(s1) = aB0; *(f32x4*)(s1 + 16) = aB1;
        *(f32x4*)(s2) = aC0; *(f32x4*)(s2 + 16) = aC1;
        *(f32x4*)(s3) = aD0; *(f32x4*)(s3 + 16) = aD1;
    }
    __syncthreads();
    if (w >= 4) {
        *(f32x4*)(s0) = *(const f32x4*)(s0) + aA0;
        *(f32x4*)(s0 + 16) = *(const f32x4*)(s0 + 16) + aA1;
        *(f32x4*)(s1) = *(const f32x4*)(s1) + aB0;
        *(f32x4*)(s1 + 16) = *(const f32x4*)(s1 + 16) + aB1;
        *(f32x4*)(s2) = *(const f32x4*)(s2) + aC0;
        *(f32x4*)(s2 + 16) = *(const f32x4*)(s2 + 16) + aC1;
        *(f32x4*)(s3) = *(const f32x4*)(s3) + aD0;
        *(f32x4*)(s3 + 16) = *(const f32x4*)(s3 + 16) + aD1;
    }
    __syncthreads();

    // 4-slot merge (plain sums) -> partial record [24 O + denom], 26-f32 stride.
    // 512 threads: q = t&63, group og = t>>6 in 0..7, 4 values each (25 total).
    const int q = t & 63, og = t >> 6;
    const float* o0 = om + (0 * 64 + q) * 36;
    const float* o1 = om + (1 * 64 + q) * 36;
    const float* o2 = om + (2 * 64 + q) * 36;
    const float* o3 = om + (3 * 64 + q) * 36;
    float* dst = part + ((size_t)((b * 2 + jh) * NPIX + tile * 64 + q)) * 26;
#pragma unroll
    for (int k = 0; k < 4; ++k) {
        const int i = og * 4 + k;
        if (i < 25) dst[i] = (o0[i] + o1[i]) + (o2[i] + o3[i]);
    }
}

// ---------------- Kernel 3: merge j-halves + 1x1 out-projection (r10 verbatim) -------
__global__ __launch_bounds__(256) void combine_kernel(
    const float* __restrict__ part,
    const float* __restrict__ wo, const float* __restrict__ bo,
    float* __restrict__ out)
{
    __shared__ float od_lds[64][25];
    __shared__ float wo_lds[64 * DD];
    __shared__ float bo_lds[64];
    const int tile = blockIdx.x, b = blockIdx.y;
    const int t = threadIdx.x;
    for (int i = t; i < 64 * DD; i += 256) wo_lds[i] = wo[i];
    if (t < 64) bo_lds[t] = bo[t];

    const int q = t & 63, c2 = t >> 6;   // c2 in 0..3
    {
        const float* pA = part + ((size_t)((b * 2 + 0) * NPIX + tile * 64 + q)) * 26;
        const float* pB = part + ((size_t)((b * 2 + 1) * NPIX + tile * 64 + q)) * 26;
#pragma unroll
        for (int k = 0; k < 7; ++k) {
            const int i = c2 * 7 + k;
            if (i < 25) od_lds[q][i] = pA[i] + pB[i];
        }
    }
    __syncthreads();

    const float inv = 1.0f / od_lds[q][24];
    float od[DD];
#pragma unroll
    for (int d = 0; d < DD; ++d) od[d] = od_lds[q][d] * inv;

    const int n_g = tile * 64 + q;
#pragma unroll
    for (int oo = 0; oo < 16; ++oo) {
        const int o = c2 * 16 + oo;
        float a = bo_lds[o];
#pragma unroll
        for (int d = 0; d < DD; ++d) a = fmaf(wo_lds[o * DD + d], od[d], a);
        out[((size_t)(b * 64 + o)) * NPIX + n_g] = a;
    }
}

extern "C" void kernel_launch(void* const* d_in, const int* in_sizes, int n_in,
                              void* d_out, int out_size, void* d_ws, size_t ws_size,
                              hipStream_t stream) {
    const float* x  = (const float*)d_in[0];
    const float* wq = (const float*)d_in[1];
    const float* bq = (const float*)d_in[2];
    const float* wk = (const float*)d_in[3];
    const float* bk = (const float*)d_in[4];
    const float* wv = (const float*)d_in[5];
    const float* bv = (const float*)d_in[6];
    const float* wo = (const float*)d_in[7];
    const float* bo = (const float*)d_in[8];
    float* out = (float*)d_out;

    unsigned short* qr  = (unsigned short*)d_ws;                 // 4*9216*32 bf16 = 2.36 MB
    unsigned short* kr  = qr + (size_t)4 * NPIX * DP;            // 2.36 MB
    unsigned short* vdn = kr + (size_t)4 * NPIX * DP;            // 4*32*9216 bf16 = 2.36 MB
    float* part = (float*)((char*)d_ws + 7077888);               // [4][2][9216][26] f32 = 7.67 MB
                                                                 // total ws use: 14.75 MB
    hipLaunchKernelGGL(qkv_proj_kernel, dim3(4 * NPIX / 256, 3), dim3(256), 0, stream,
                       x, wq, bq, wk, bk, wv, bv, qr, kr, vdn);
    hipLaunchKernelGGL(attn_kernel, dim3(NPIX / 64, 2, 4), dim3(512), 0, stream,
                       qr, kr, vdn, part);
    hipLaunchKernelGGL(combine_kernel, dim3(NPIX / 64, 4), dim3(256), 0, stream,
                       part, wo, bo, out);
}